// Round 14
// baseline (185.551 us; speedup 1.0000x reference)
//
#include <hip/hip_runtime.h>
#include <hip/hip_bf16.h>
#include <cstdint>
#include <cstddef>

#define T_ 8
#define N_ 16384
#define D_ 512
#define H_ 1024
#define O_ 64
#define IDX_COUNT (T_*N_)   // 131072

typedef __attribute__((ext_vector_type(4))) float f32x4;
typedef __attribute__((ext_vector_type(4))) int   i32x4;
typedef __attribute__((ext_vector_type(8))) int   i32x8;

#define WSCALE 64.0f        // weights pre-scaled into fp8 normal range
#define INV_WSCALE 0.015625f
#define UNIT_SCALE 0x7f7f7f7f   // e8m0 exponent 127 -> x1.0 for every 32-elem block

// pack 4 floats -> 4 fp8 e4m3 bytes (RNE, saturating)
__device__ __forceinline__ int pack4fp8(f32x4 v) {
  int t = __builtin_amdgcn_cvt_pk_fp8_f32(v[0], v[1], 0, false);
  return  __builtin_amdgcn_cvt_pk_fp8_f32(v[2], v[3], t, true);
}
// pack 8 floats -> 8 fp8 bytes in one 64-bit value (GEMM2 path, verified R7)
__device__ __forceinline__ long long pack8fp8(f32x4 a, f32x4 b) {
  int lo = pack4fp8(a), hi = pack4fp8(b);
  return (long long)(unsigned)lo | ((long long)hi << 32);
}

// MX-scaled fp8 MFMA, K=128, unit scales (both operands fp8 e4m3)
__device__ __forceinline__ f32x4 mfma128(i32x8 a, i32x8 b, f32x4 c) {
  return __builtin_amdgcn_mfma_scale_f32_16x16x128_f8f6f4(
      a, b, c, 0, 0, 0, UNIT_SCALE, 0, UNIT_SCALE);
}

// ---------------- indices kernel: node_type is sorted repeat(arange(T)) -> indices == arange
__global__ void idx_kernel(float* __restrict__ out) {
  int i = blockIdx.x * 256 + threadIdx.x;
  out[i] = (float)i;
}

// ---------------- prep_w1: W1 f32 -> fp8 K=128 A-fragment tiles (verbatim R11) ----------
__global__ void prep_w1(const float* __restrict__ W1, char* __restrict__ ws) {
  int bid = blockIdx.x;            // t*64 + hc*4 + kk
  int kk = bid & 3, hc = (bid >> 2) & 15, t = bid >> 6;
  int tid = threadIdx.x;
  char* dst = ws + (size_t)bid * 8192;
  const float* src = W1 + ((size_t)t*D_ + kk*128)*H_ + hc*64;
#pragma unroll
  for (int i = 0; i < 2; i++) {
    int ch = i*256 + tid;          // 512 16B chunks
    int lane = ch & 63, hf = (ch >> 6) & 3, q = ch >> 8;
    int r = lane & 15, g = lane >> 4;
    i32x4 pk;
#pragma unroll
    for (int e4 = 0; e4 < 4; e4++) {
      f32x4 v;
#pragma unroll
      for (int j = 0; j < 4; j++)
        v[j] = src[(size_t)(g*32 + q*16 + e4*4 + j)*H_ + hf*16 + r] * WSCALE;
      pk[e4] = pack4fp8(v);
    }
    *(i32x4*)(dst + q*4096 + ((hf*64 + lane) << 4)) = pk;
  }
}

// ---------------- prep_w2: W2 f32 -> fp8 A-frags, scrambled k (verbatim R7-R13) ----------
__global__ void prep_w2(const float* __restrict__ W2, char* __restrict__ ws) {
  int bid = blockIdx.x;            // t*16 + hc
  int hc = bid & 15, t = bid >> 4;
  int tid = threadIdx.x;
  char* dst = ws + (size_t)bid * 4096;
  const float* src = W2 + ((size_t)t*H_ + hc*64)*O_;
#pragma unroll
  for (int i = 0; i < 2; i++) {
    int ch = i*256 + tid;          // 512 8B chunks
    int lane = ch & 63, of = (ch >> 6) & 3, kb = ch >> 8;
    int r = lane & 15, g = lane >> 4;
    f32x4 a, b;
#pragma unroll
    for (int j = 0; j < 4; j++) {
      a[j] = src[(size_t)(kb*32 +      g*4 + j)*O_ + of*16 + r] * WSCALE;   // m=0
      b[j] = src[(size_t)(kb*32 + 16 + g*4 + j)*O_ + of*16 + r] * WSCALE;   // m=1
    }
    *(long long*)(dst + ch*8) = pack8fp8(a, b);
  }
}

// ---------------- fused GEMM1 -> sigmoid -> GEMM2: pure register dataflow ----------------
// NO LDS, NO barriers, NO inline asm. One wave per block; W1/W2/b1 fragments are loaded
// straight into registers from the prep images (lane-linear -> plain dwordx4 loads with
// folded offsets). The compiler does precise per-register vmcnt tracking + pipelining
// for VMEM->VGPR loads (the path it is proven good at), sidestepping the conservative
// waits of the global_load_lds -> ds_read path that R7-R13 evidence indicts.

// load the 4 hf-fragments of W1 tile q into dst[0..3]
#define LDW1(Q, DST) do {                                                    \
  const char* p_ = w1base + (size_t)(Q)*8192 + (lane << 4);                  \
  _Pragma("unroll")                                                          \
  for (int hf_ = 0; hf_ < 4; hf_++) {                                        \
    i32x4 lo_ = *(const i32x4*)(p_ +        hf_*1024);                       \
    i32x4 hi_ = *(const i32x4*)(p_ + 4096 + hf_*1024);                       \
    (DST)[hf_] = __builtin_shufflevector(lo_, hi_, 0,1,2,3,4,5,6,7);         \
  }                                                                          \
} while (0)

// 8 MFMAs of one K=128 tile against both row-fragments
#define MFMA4(WSRC, KK) do {                                                 \
  _Pragma("unroll")                                                          \
  for (int hf_ = 0; hf_ < 4; hf_++) {                                        \
    hacc[hf_][0] = mfma128((WSRC)[hf_], xf[0][KK], hacc[hf_][0]);            \
    hacc[hf_][1] = mfma128((WSRC)[hf_], xf[1][KK], hacc[hf_][1]);            \
  }                                                                          \
} while (0)

__global__ __launch_bounds__(64, 2) void gemm_fused(
    const float* __restrict__ x, const float* __restrict__ b1,
    const float* __restrict__ b2, const char* __restrict__ wsw1,
    const char* __restrict__ wsw2, float* __restrict__ out)
{
  const int lane = threadIdx.x;            // one wave per block
  // XCD swizzle: 4096 blocks, type = XCD (W1_t 0.5MB + W2_t stay XCD-L2-hot)
  const int bid = ((blockIdx.x & 7) << 9) | (blockIdx.x >> 3);
  const int t = bid >> 9;
  const int rblk = bid & 511;              // 512 row-blocks of 32 rows per type
  const int r = lane & 15;
  const int g = lane >> 4;

  const char* w1base = wsw1 + (size_t)t * (64*8192);   // 64 tiles of 8KB
  const char* w2base = wsw2 + (size_t)t * (16*4096);

  // x rows -> persistent fp8 K=128 B-fragments (i32x8), read exactly once.
  // xf[nf][kk]: lane holds x[n = rblk*32 + nf*16 + r][k = kk*128 + g*32 + e]
  i32x8 xf[2][4];
#pragma unroll
  for (int nf = 0; nf < 2; nf++) {
    const float* xr = x + ((size_t)(t*N_ + rblk*32 + nf*16 + r))*D_ + g*32;
#pragma unroll
    for (int kk = 0; kk < 4; kk++) {
      const f32x4* p = (const f32x4*)(xr + kk*128);
      i32x8 a;
#pragma unroll
      for (int q = 0; q < 8; q++) a[q] = pack4fp8(p[q]);
      xf[nf][kk] = a;
    }
  }

  f32x4 oacc[4][2];   // O^T frags [of][nf]: lane o = of*16+g*4+j, n = nf*16+r
#pragma unroll
  for (int i = 0; i < 4; i++)
#pragma unroll
    for (int nf = 0; nf < 2; nf++) oacc[i][nf] = (f32x4){0.f,0.f,0.f,0.f};

  i32x8 wA[4], wB[4];   // depth-1 double buffer of W1 tile fragments (static indexing)
  LDW1(0, wA);

#pragma unroll 1
  for (int hc = 0; hc < 16; hc++) {
    f32x4 hacc[4][2];  // H^T frags [hf][nf]: lane h = hf*16+g*4+j, n = nf*16+r
#pragma unroll
    for (int i = 0; i < 4; i++)
#pragma unroll
      for (int nf = 0; nf < 2; nf++) hacc[i][nf] = (f32x4){0.f,0.f,0.f,0.f};

    // W2 chunk for this hc -> registers early (used after GEMM1; latency hidden)
    long long w2r[8];
    {
      const char* wsrc = w2base + (size_t)hc*4096;
#pragma unroll
      for (int c = 0; c < 8; c++)
        w2r[c] = *(const long long*)(wsrc + ((c*64 + lane) << 3));
    }

    const int q0 = hc*4;
    // prefetch(q+1) || compute(q): explicit A/B alternation, parity-stable across hc
    LDW1(q0 + 1, wB);                    MFMA4(wA, 0);
    LDW1(q0 + 2, wA);                    MFMA4(wB, 1);
    LDW1(q0 + 3, wB);                    MFMA4(wA, 2);
    { int qn = q0 + 4; if (qn > 63) qn = 63;
      LDW1(qn, wA); }                    MFMA4(wB, 3);

    // bias + sigmoid in place + pack, then GEMM2 (scrambled-k cancel, verified R7)
#pragma unroll
    for (int hf = 0; hf < 4; hf++) {
      f32x4 bv = *(const f32x4*)(b1 + t*H_ + hc*64 + hf*16 + g*4);
#pragma unroll
      for (int nf = 0; nf < 2; nf++)
#pragma unroll
        for (int j = 0; j < 4; j++) {
          float v = hacc[hf][nf][j] * INV_WSCALE + bv[j];
          hacc[hf][nf][j] = __builtin_amdgcn_rcpf(1.f + __expf(-v));
        }
    }
    long long hb[2][2];
#pragma unroll
    for (int kb = 0; kb < 2; kb++)
#pragma unroll
      for (int nf = 0; nf < 2; nf++)
        hb[kb][nf] = pack8fp8(hacc[2*kb][nf], hacc[2*kb+1][nf]);
#pragma unroll
    for (int kb = 0; kb < 2; kb++)
#pragma unroll
      for (int of = 0; of < 4; of++) {
        oacc[of][0] = __builtin_amdgcn_mfma_f32_16x16x32_fp8_fp8(w2r[kb*4+of], hb[kb][0], oacc[of][0], 0,0,0);
        oacc[of][1] = __builtin_amdgcn_mfma_f32_16x16x32_fp8_fp8(w2r[kb*4+of], hb[kb][1], oacc[of][1], 0,0,0);
      }
  }

  // epilogue: direct f32x4 stores (un-scale W2).
  const float* b2p = b2 + t*O_;
  float* obase = out + IDX_COUNT + ((size_t)(t*N_ + rblk*32))*O_;
#pragma unroll
  for (int nf = 0; nf < 2; nf++)
#pragma unroll
    for (int of = 0; of < 4; of++) {
      f32x4 bv = *(const f32x4*)(b2p + of*16 + g*4);
      f32x4 v;
#pragma unroll
      for (int j = 0; j < 4; j++) v[j] = oacc[of][nf][j] * INV_WSCALE + bv[j];
      *(f32x4*)(obase + (size_t)(nf*16 + r)*O_ + of*16 + g*4) = v;
    }
}

// ---------------- naive f32 fallback (only if ws too small) ----------------
__global__ void naive_kernel(const float* __restrict__ x, const float* __restrict__ W1,
                             const float* __restrict__ b1, const float* __restrict__ W2,
                             const float* __restrict__ b2, float* __restrict__ out) {
  const int row = blockIdx.x;
  const int t = row >> 14;
  __shared__ float xs[512];
  __shared__ float hs[1024];
  const float* xr = x + (size_t)row * D_;
  for (int i = threadIdx.x; i < D_; i += 256) xs[i] = xr[i];
  __syncthreads();
  const float* w1t = W1 + (size_t)t * D_ * H_;
  for (int h = threadIdx.x; h < H_; h += 256) {
    float acc = b1[t*H_ + h];
    for (int k = 0; k < D_; k++) acc += xs[k] * w1t[(size_t)k*H_ + h];
    hs[h] = 1.f / (1.f + __expf(-acc));
  }
  __syncthreads();
  const float* w2t = W2 + (size_t)t * H_ * O_;
  for (int o = threadIdx.x; o < O_; o += 256) {
    float acc = b2[t*O_ + o];
    for (int k = 0; k < H_; k++) acc += hs[k] * w2t[k*O_ + o];
    out[IDX_COUNT + (size_t)row*O_ + o] = acc;
  }
}

extern "C" void kernel_launch(void* const* d_in, const int* in_sizes, int n_in,
                              void* d_out, int out_size, void* d_ws, size_t ws_size,
                              hipStream_t stream) {
  const float* x  = (const float*)d_in[0];
  const float* W1 = (const float*)d_in[1];
  const float* b1 = (const float*)d_in[2];
  const float* W2 = (const float*)d_in[3];
  const float* b2 = (const float*)d_in[4];
  float* out = (float*)d_out;

  idx_kernel<<<IDX_COUNT/256, 256, 0, stream>>>(out);

  const size_t w1_bytes = (size_t)T_*64*8192;    // 4,194,304
  const size_t w2_bytes = (size_t)T_*16*4096;    //   524,288
  if (ws_size >= w1_bytes + w2_bytes) {
    char* wsw1 = (char*)d_ws;
    char* wsw2 = wsw1 + w1_bytes;
    prep_w1<<<T_*64, 256, 0, stream>>>(W1, wsw1);
    prep_w2<<<T_*16, 256, 0, stream>>>(W2, wsw2);
    gemm_fused<<<T_*(N_/32), 64, 0, stream>>>(x, b1, b2, wsw1, wsw2, out);
  } else {
    naive_kernel<<<T_*N_, 256, 0, stream>>>(x, W1, b1, W2, b2, out);
  }
}

// Round 15
// 156.267 us; speedup vs baseline: 1.1874x; 1.1874x over previous
//
#include <hip/hip_runtime.h>
#include <hip/hip_bf16.h>
#include <cstdint>
#include <cstddef>

#define T_ 8
#define N_ 16384
#define D_ 512
#define H_ 1024
#define O_ 64
#define IDX_COUNT (T_*N_)   // 131072

typedef __attribute__((ext_vector_type(4))) float f32x4;
typedef __attribute__((ext_vector_type(4))) int   i32x4;
typedef __attribute__((ext_vector_type(8))) int   i32x8;

#define WSCALE 64.0f        // weights pre-scaled into fp8 normal range
#define INV_WSCALE 0.015625f
#define UNIT_SCALE 0x7f7f7f7f   // e8m0 exponent 127 -> x1.0 for every 32-elem block

// pack 4 floats -> 4 fp8 e4m3 bytes (RNE, saturating)
__device__ __forceinline__ int pack4fp8(f32x4 v) {
  int t = __builtin_amdgcn_cvt_pk_fp8_f32(v[0], v[1], 0, false);
  return  __builtin_amdgcn_cvt_pk_fp8_f32(v[2], v[3], t, true);
}
// pack 8 floats -> 8 fp8 bytes in one 64-bit value (GEMM2 path, verified R7)
__device__ __forceinline__ long long pack8fp8(f32x4 a, f32x4 b) {
  int lo = pack4fp8(a), hi = pack4fp8(b);
  return (long long)(unsigned)lo | ((long long)hi << 32);
}

// MX-scaled fp8 MFMA, K=128, unit scales (both operands fp8 e4m3)
__device__ __forceinline__ f32x4 mfma128(i32x8 a, i32x8 b, f32x4 c) {
  return __builtin_amdgcn_mfma_scale_f32_16x16x128_f8f6f4(
      a, b, c, 0, 0, 0, UNIT_SCALE, 0, UNIT_SCALE);
}

// ---------------- indices kernel: node_type is sorted repeat(arange(T)) -> indices == arange
__global__ void idx_kernel(float* __restrict__ out) {
  int i = blockIdx.x * 256 + threadIdx.x;
  out[i] = (float)i;
}

// ---------------- prep_w1: W1 f32 -> fp8 K=128 A-fragment tiles (verbatim R11) ----------
__global__ void prep_w1(const float* __restrict__ W1, char* __restrict__ ws) {
  int bid = blockIdx.x;            // t*64 + hc16*4 + kk
  int kk = bid & 3, hc = (bid >> 2) & 15, t = bid >> 6;
  int tid = threadIdx.x;
  char* dst = ws + (size_t)bid * 8192;
  const float* src = W1 + ((size_t)t*D_ + kk*128)*H_ + hc*64;
#pragma unroll
  for (int i = 0; i < 2; i++) {
    int ch = i*256 + tid;          // 512 16B chunks
    int lane = ch & 63, hf = (ch >> 6) & 3, q = ch >> 8;
    int r = lane & 15, g = lane >> 4;
    i32x4 pk;
#pragma unroll
    for (int e4 = 0; e4 < 4; e4++) {
      f32x4 v;
#pragma unroll
      for (int j = 0; j < 4; j++)
        v[j] = src[(size_t)(g*32 + q*16 + e4*4 + j)*H_ + hf*16 + r] * WSCALE;
      pk[e4] = pack4fp8(v);
    }
    *(i32x4*)(dst + q*4096 + ((hf*64 + lane) << 4)) = pk;
  }
}

// ---------------- prep_w2: W2 f32 -> fp8 A-frags, scrambled k (verbatim R7-R14) ----------
__global__ void prep_w2(const float* __restrict__ W2, char* __restrict__ ws) {
  int bid = blockIdx.x;            // t*16 + c
  int hc = bid & 15, t = bid >> 4;
  int tid = threadIdx.x;
  char* dst = ws + (size_t)bid * 4096;
  const float* src = W2 + ((size_t)t*H_ + hc*64)*O_;
#pragma unroll
  for (int i = 0; i < 2; i++) {
    int ch = i*256 + tid;          // 512 8B chunks
    int lane = ch & 63, of = (ch >> 6) & 3, kb = ch >> 8;
    int r = lane & 15, g = lane >> 4;
    f32x4 a, b;
#pragma unroll
    for (int j = 0; j < 4; j++) {
      a[j] = src[(size_t)(kb*32 +      g*4 + j)*O_ + of*16 + r] * WSCALE;   // m=0
      b[j] = src[(size_t)(kb*32 + 16 + g*4 + j)*O_ + of*16 + r] * WSCALE;   // m=1
    }
    *(long long*)(dst + ch*8) = pack8fp8(a, b);
  }
}

// ---------------- fused GEMM1 -> sigmoid -> GEMM2 ----------------
__device__ __forceinline__ void gl_lds16(const void* g, void* l) {
  __builtin_amdgcn_global_load_lds((const __attribute__((address_space(1))) unsigned int*)g,
                                   (__attribute__((address_space(3))) unsigned int*)l, 16, 0, 0);
}

// FAT PHASES: 128 h per hc (hf=0..7), 8 hc x 4 phases = 32 phases total.
// Per phase: one 16KB W1 tile PAIR (tiles ta=(p>>2)*8+(p&3) and ta+4) -> 16 mfma128/wave.
// Depth-3 pair-slot rotation (R8-verified), stage-ahead 2. vmcnt by queue sim:
// S(kk0)=6 (4 w1 + 2 w2), else 4 -> N = S(p-1) = {4,6,4,4}. Clamped tails land in
// provably-dead slots (R13 pattern).
#define PHASE_K(HC, KK, NCNT) do {                                                      \
  asm volatile("s_waitcnt vmcnt(" #NCNT ")" ::: "memory");                              \
  __builtin_amdgcn_s_barrier();                                                         \
  asm volatile("" ::: "memory");                                                        \
  {                                                                                     \
    int pp = (HC)*4 + (KK) + 2; if (pp > 31) pp = 31;                                   \
    int wr = rd + 2; if (wr >= 3) wr -= 3;                                              \
    const char* gA = w1base + (size_t)(((pp >> 2) << 3) + (pp & 3)) * 8192;             \
    char* nb = &w1buf[0][0] + wr*16384;                                                 \
    gl_lds16(gA +         tid*16, nb +         w*1024);                                 \
    gl_lds16(gA +  4096 + tid*16, nb +  4096 + w*1024);                                 \
    gl_lds16(gA + 32768 + tid*16, nb +  8192 + w*1024);   /* tile ta+4 */               \
    gl_lds16(gA + 36864 + tid*16, nb + 12288 + w*1024);                                 \
  }                                                                                     \
  if ((KK) == 0) {                                                                      \
    int c2 = (HC)*2 + 2, c3 = (HC)*2 + 3;                                               \
    if (c2 > 15) c2 = 15; if (c3 > 15) c3 = 15;                                         \
    char* wb = &w2buf[((HC)+1)&1][0];                                                   \
    gl_lds16(w2base + (size_t)c2*4096 + tid*16, wb +        w*1024);                    \
    gl_lds16(w2base + (size_t)c3*4096 + tid*16, wb + 4096 + w*1024);                    \
  }                                                                                     \
  {                                                                                     \
    const char* cur = &w1buf[0][0] + rd*16384;                                          \
    __builtin_amdgcn_s_setprio(1);                                                      \
    _Pragma("unroll")                                                                   \
    for (int hf = 0; hf < 8; hf++) {                                                    \
      const char* tb = cur + ((hf & 4) << 11) + ((hf & 3) << 10);                       \
      i32x4 lo = *(const i32x4*)(tb +        (lane << 4));                              \
      i32x4 hi = *(const i32x4*)(tb + 4096 + (lane << 4));                              \
      i32x8 a = __builtin_shufflevector(lo, hi, 0,1,2,3,4,5,6,7);                       \
      hacc[hf][0] = mfma128(a, xf[0][KK], hacc[hf][0]);                                 \
      hacc[hf][1] = mfma128(a, xf[1][KK], hacc[hf][1]);                                 \
    }                                                                                   \
    __builtin_amdgcn_s_setprio(0);                                                      \
  }                                                                                     \
  rd = (rd == 2) ? 0 : rd + 1;                                                          \
} while (0)

// 256 thr / 4 waves / 128 rows per block (32 rows per wave). LDS 68KB -> 2 blocks/CU.
__global__ __launch_bounds__(256, 2) void gemm_fused(
    const float* __restrict__ x, const float* __restrict__ b1,
    const float* __restrict__ b2, const char* __restrict__ wsw1,
    const char* __restrict__ wsw2, float* __restrict__ out)
{
  __shared__ __align__(16) char w1buf[3][16384];   // depth-3 circular: 16KB W1 tile PAIRS
  __shared__ __align__(16) char w2buf[2][8192];    // W2: 2 chunks (128 h) per hc, parity
  __shared__ __align__(16) float b1lds[1024];      // b1[t] (keeps loop VMEM-pure)

  const int tid = threadIdx.x;
  const int lane = tid & 63;
  const int w = tid >> 6;                  // wave 0..3, owns 32 rows
  // XCD swizzle: 1024 blocks -> one type per XCD
  const int bid = ((blockIdx.x & 7) << 7) | (blockIdx.x >> 3);
  const int t = bid >> 7;
  const int rblk = bid & 127;              // 128 row-blocks of 128 rows per type
  const int r = lane & 15;
  const int g = lane >> 4;

  const char* w1base = wsw1 + (size_t)t * (64*8192);   // 64 tiles of 8KB
  const char* w2base = wsw2 + (size_t)t * (16*4096);

  // prologue: pairs p=0 (tiles 0,4 -> slot 0), p=1 (tiles 1,5 -> slot 1),
  // w2 chunks 0,1 -> w2buf[0], b1; x loads; syncthreads drains all (vmcnt -> 0)
  gl_lds16(w1base +          tid*16, &w1buf[0][0] +         w*1024);   // tile 0 q0
  gl_lds16(w1base +   4096 + tid*16, &w1buf[0][0] +  4096 + w*1024);  // tile 0 q1
  gl_lds16(w1base +  32768 + tid*16, &w1buf[0][0] +  8192 + w*1024);  // tile 4 q0
  gl_lds16(w1base +  36864 + tid*16, &w1buf[0][0] + 12288 + w*1024);  // tile 4 q1
  gl_lds16(w1base +   8192 + tid*16, &w1buf[1][0] +         w*1024);  // tile 1 q0
  gl_lds16(w1base +  12288 + tid*16, &w1buf[1][0] +  4096 + w*1024);  // tile 1 q1
  gl_lds16(w1base +  40960 + tid*16, &w1buf[1][0] +  8192 + w*1024);  // tile 5 q0
  gl_lds16(w1base +  45056 + tid*16, &w1buf[1][0] + 12288 + w*1024);  // tile 5 q1
  gl_lds16(w2base +          tid*16, &w2buf[0][0] +         w*1024);  // chunk 0
  gl_lds16(w2base +   4096 + tid*16, &w2buf[0][0] +  4096 + w*1024);  // chunk 1
  gl_lds16((const char*)(b1 + (size_t)t*H_) + tid*16, (char*)b1lds + w*1024);

  // x rows -> persistent fp8 K=128 B-fragments (i32x8), read exactly once.
  // xf[nf][kk]: lane holds x[n = rblk*128 + w*32 + nf*16 + r][k = kk*128 + g*32 + e]
  i32x8 xf[2][4];
#pragma unroll
  for (int nf = 0; nf < 2; nf++) {
    const float* xr = x + ((size_t)(t*N_ + rblk*128 + w*32 + nf*16 + r))*D_ + g*32;
#pragma unroll
    for (int kk = 0; kk < 4; kk++) {
      const f32x4* p = (const f32x4*)(xr + kk*128);
      i32x8 a;
#pragma unroll
      for (int q = 0; q < 8; q++) a[q] = pack4fp8(p[q]);
      xf[nf][kk] = a;
    }
  }

  f32x4 oacc[4][2];   // O^T frags [of][nf]: lane o = of*16+g*4+j, n = nf*16+r
#pragma unroll
  for (int i = 0; i < 4; i++)
#pragma unroll
    for (int nf = 0; nf < 2; nf++) oacc[i][nf] = (f32x4){0.f,0.f,0.f,0.f};

  __syncthreads();   // full drain once: slots 0,1 + w2 chunks 0,1 + b1 ready

  int rd = 0;        // rotating pair-slot index (R8-verified pattern)

#pragma unroll 1     // rolled: body I$-resident, rd loop-carried
  for (int hc = 0; hc < 8; hc++) {
    f32x4 hacc[8][2];  // H^T frags [hf][nf]: lane h = hc*128 + hf*16 + g*4 + j, n = nf*16+r
#pragma unroll
    for (int i = 0; i < 8; i++)
#pragma unroll
      for (int nf = 0; nf < 2; nf++) hacc[i][nf] = (f32x4){0.f,0.f,0.f,0.f};

    PHASE_K(hc, 0, 4);
    PHASE_K(hc, 1, 6);
    PHASE_K(hc, 2, 4);
    PHASE_K(hc, 3, 4);

    // bias + sigmoid in place + pack, then GEMM2 (64-h-local scramble, verified R7)
#pragma unroll
    for (int hf = 0; hf < 8; hf++) {
      f32x4 bv = *(const f32x4*)(b1lds + hc*128 + hf*16 + g*4);
#pragma unroll
      for (int nf = 0; nf < 2; nf++)
#pragma unroll
        for (int j = 0; j < 4; j++) {
          float v = hacc[hf][nf][j] * INV_WSCALE + bv[j];
          hacc[hf][nf][j] = __builtin_amdgcn_rcpf(1.f + __expf(-v));
        }
    }
    long long hb[4][2];
#pragma unroll
    for (int m2 = 0; m2 < 2; m2++)
#pragma unroll
      for (int kb = 0; kb < 2; kb++)
#pragma unroll
        for (int nf = 0; nf < 2; nf++)
          hb[m2*2+kb][nf] = pack8fp8(hacc[m2*4+kb*2][nf], hacc[m2*4+kb*2+1][nf]);
    const char* curw2 = &w2buf[hc & 1][0];
    __builtin_amdgcn_s_setprio(1);
#pragma unroll
    for (int m2 = 0; m2 < 2; m2++)
#pragma unroll
      for (int kb = 0; kb < 2; kb++)
#pragma unroll
        for (int of = 0; of < 4; of++) {
          long long wf = *(const long long*)(curw2 + m2*4096 + (((kb*4 + of)*64 + lane) << 3));
          oacc[of][0] = __builtin_amdgcn_mfma_f32_16x16x32_fp8_fp8(wf, hb[m2*2+kb][0], oacc[of][0], 0,0,0);
          oacc[of][1] = __builtin_amdgcn_mfma_f32_16x16x32_fp8_fp8(wf, hb[m2*2+kb][1], oacc[of][1], 0,0,0);
        }
    __builtin_amdgcn_s_setprio(0);
  }

  // epilogue: direct f32x4 stores (un-scale W2), no LDS.
  const float* b2p = b2 + t*O_;
  float* obase = out + IDX_COUNT + ((size_t)(t*N_ + rblk*128 + w*32))*O_;
#pragma unroll
  for (int nf = 0; nf < 2; nf++)
#pragma unroll
    for (int of = 0; of < 4; of++) {
      f32x4 bv = *(const f32x4*)(b2p + of*16 + g*4);
      f32x4 v;
#pragma unroll
      for (int j = 0; j < 4; j++) v[j] = oacc[of][nf][j] * INV_WSCALE + bv[j];
      *(f32x4*)(obase + (size_t)(nf*16 + r)*O_ + of*16 + g*4) = v;
    }
}

// ---------------- naive f32 fallback (only if ws too small) ----------------
__global__ void naive_kernel(const float* __restrict__ x, const float* __restrict__ W1,
                             const float* __restrict__ b1, const float* __restrict__ W2,
                             const float* __restrict__ b2, float* __restrict__ out) {
  const int row = blockIdx.x;
  const int t = row >> 14;
  __shared__ float xs[512];
  __shared__ float hs[1024];
  const float* xr = x + (size_t)row * D_;
  for (int i = threadIdx.x; i < D_; i += 256) xs[i] = xr[i];
  __syncthreads();
  const float* w1t = W1 + (size_t)t * D_ * H_;
  for (int h = threadIdx.x; h < H_; h += 256) {
    float acc = b1[t*H_ + h];
    for (int k = 0; k < D_; k++) acc += xs[k] * w1t[(size_t)k*H_ + h];
    hs[h] = 1.f / (1.f + __expf(-acc));
  }
  __syncthreads();
  const float* w2t = W2 + (size_t)t * H_ * O_;
  for (int o = threadIdx.x; o < O_; o += 256) {
    float acc = b2[t*O_ + o];
    for (int k = 0; k < H_; k++) acc += hs[k] * w2t[k*O_ + o];
    out[IDX_COUNT + (size_t)row*O_ + o] = acc;
  }
}

extern "C" void kernel_launch(void* const* d_in, const int* in_sizes, int n_in,
                              void* d_out, int out_size, void* d_ws, size_t ws_size,
                              hipStream_t stream) {
  const float* x  = (const float*)d_in[0];
  const float* W1 = (const float*)d_in[1];
  const float* b1 = (const float*)d_in[2];
  const float* W2 = (const float*)d_in[3];
  const float* b2 = (const float*)d_in[4];
  float* out = (float*)d_out;

  idx_kernel<<<IDX_COUNT/256, 256, 0, stream>>>(out);

  const size_t w1_bytes = (size_t)T_*64*8192;    // 4,194,304
  const size_t w2_bytes = (size_t)T_*16*4096;    //   524,288
  if (ws_size >= w1_bytes + w2_bytes) {
    char* wsw1 = (char*)d_ws;
    char* wsw2 = wsw1 + w1_bytes;
    prep_w1<<<T_*64, 256, 0, stream>>>(W1, wsw1);
    prep_w2<<<T_*16, 256, 0, stream>>>(W2, wsw2);
    gemm_fused<<<T_*(N_/128), 256, 0, stream>>>(x, b1, b2, wsw1, wsw2, out);
  } else {
    naive_kernel<<<T_*N_, 256, 0, stream>>>(x, W1, b1, W2, b2, out);
  }
}